// Round 1
// baseline (440.059 us; speedup 1.0000x reference)
//
#include <hip/hip_runtime.h>
#include <hip/hip_fp16.h>
#include <hip/hip_cooperative_groups.h>

namespace cg = cooperative_groups;

// Problem constants
constexpr int BN = 64, CH = 3, HH = 512, WW = 512;
constexpr int HO = 256, WO = 256;
constexpr int HW = HH * WW;              // 262144
constexpr int HOWO = HO * WO;            // 65536
constexpr float EPS_F = 1e-8f;

constexpr int TPB = 256;
constexpr int GROUPS = BN * HO * (WO / 4);   // 1,048,576 groups of 4 patches

// --- fused cooperative config: exactly co-resident (4 blocks/CU x 256 CU) ---
constexpr int FBLK = 1024;
constexpr int FTHR = FBLK * TPB;             // 262,144 threads
constexpr int FITERS = GROUPS / FTHR;        // 4 groups (16 patches) per thread

// --- fallback (previous verified 3-kernel path) config ---
constexpr int ABLOCKS = 2048;
constexpr int AT = ABLOCKS * TPB;
constexpr int AITERS = GROUPS / AT;          // 2
constexpr int CBLOCKS = GROUPS / TPB;        // 4096
constexpr size_t GRAY_HALFS = (size_t)GROUPS * 16;

// tanh(x) = 1 - 2/(e^{2x}+1) via hw exp2 + rcp (abs err ~1e-6, saturates correctly)
__device__ __forceinline__ float fast_tanh(float x) {
    float t = __builtin_amdgcn_exp2f(x * 2.8853900817779268f);  // e^{2x}
    return 1.0f - 2.0f * __builtin_amdgcn_rcpf(t + 1.0f);
}

// ============================ FUSED PATH ============================
// One persistent cooperative kernel:
//   Phase A: gray = mean(x,C) kept in REGISTERS (fp16x2), block min/max -> part[]
//   grid.sync()
//   Phase B: every block redundantly reduces 1024 partial pairs (8 KB, L2-hot,
//            deterministic), then quantum chain + projection from registers.
__global__ __launch_bounds__(TPB, 4) void k_fused(const float* __restrict__ x,
                                                  const float* __restrict__ wts,
                                                  const float* __restrict__ pw,
                                                  const float* __restrict__ pb,
                                                  float* __restrict__ part,
                                                  float* __restrict__ out) {
    const int tid = blockIdx.x * TPB + threadIdx.x;
    const float c13 = 1.0f / 3.0f;
    float vmin = __int_as_float(0x7F800000);
    float vmax = __int_as_float(0xFF800000);

    __half2 g[FITERS][8];   // 32 VGPRs of gray data held across the grid sync

    #pragma unroll
    for (int it = 0; it < FITERS; ++it) {
        const int grp = it * FTHR + tid;     // group of 4 consecutive patches
        const int b   = grp >> 14;           // 16384 groups per image
        const int rem = grp & 16383;
        const int ho  = rem >> 6;            // 64 groups per patch-row
        const int wp  = rem & 63;
        const float* base = x + b * (CH * HW) + (2 * ho) * WW + 8 * wp;

        float row0[8], row1[8];
        #pragma unroll
        for (int c = 0; c < CH; ++c) {
            const float* pc = base + c * HW;
            float4 u0 = *(const float4*)(pc);
            float4 u1 = *(const float4*)(pc + 4);
            float4 v0 = *(const float4*)(pc + WW);
            float4 v1 = *(const float4*)(pc + WW + 4);
            float uu[8] = {u0.x, u0.y, u0.z, u0.w, u1.x, u1.y, u1.z, u1.w};
            float vv[8] = {v0.x, v0.y, v0.z, v0.w, v1.x, v1.y, v1.z, v1.w};
            if (c == 0) {
                #pragma unroll
                for (int k = 0; k < 8; ++k) { row0[k] = uu[k]; row1[k] = vv[k]; }
            } else {
                #pragma unroll
                for (int k = 0; k < 8; ++k) { row0[k] += uu[k]; row1[k] += vv[k]; }
            }
        }
        #pragma unroll
        for (int k = 0; k < 8; ++k) {
            row0[k] *= c13; row1[k] *= c13;
            vmin = fminf(vmin, fminf(row0[k], row1[k]));
            vmax = fmaxf(vmax, fmaxf(row0[k], row1[k]));
        }
        #pragma unroll
        for (int p = 0; p < 4; ++p) {
            g[it][2 * p]     = __floats2half2_rn(row0[2 * p], row0[2 * p + 1]);
            g[it][2 * p + 1] = __floats2half2_rn(row1[2 * p], row1[2 * p + 1]);
        }
    }

    // block min/max reduce -> per-block partials (plain stores, deterministic)
    #pragma unroll
    for (int off = 32; off > 0; off >>= 1) {
        vmin = fminf(vmin, __shfl_down(vmin, off, 64));
        vmax = fmaxf(vmax, __shfl_down(vmax, off, 64));
    }
    __shared__ float sm[8];
    const int lane = threadIdx.x & 63, wid = threadIdx.x >> 6;
    if (lane == 0) { sm[wid] = vmin; sm[4 + wid] = vmax; }
    __syncthreads();
    if (threadIdx.x == 0) {
        part[2 * blockIdx.x]     = fminf(fminf(sm[0], sm[1]), fminf(sm[2], sm[3]));
        part[2 * blockIdx.x + 1] = fmaxf(fmaxf(sm[4], sm[5]), fmaxf(sm[6], sm[7]));
    }

    cg::this_grid().sync();

    // every block redundantly reduces the 1024 partial pairs (8 KB, L2-hot)
    float m = __int_as_float(0x7F800000);
    float M = __int_as_float(0xFF800000);
    #pragma unroll
    for (int i = 0; i < FBLK / TPB; ++i) {
        const int j = i * TPB + threadIdx.x;
        m = fminf(m, part[2 * j]);
        M = fmaxf(M, part[2 * j + 1]);
    }
    #pragma unroll
    for (int off = 32; off > 0; off >>= 1) {
        m = fminf(m, __shfl_down(m, off, 64));
        M = fmaxf(M, __shfl_down(M, off, 64));
    }
    if (lane == 0) { sm[wid] = m; sm[4 + wid] = M; }
    __syncthreads();
    const float pmin = fminf(fminf(sm[0], sm[1]), fminf(sm[2], sm[3]));
    const float pmax = fmaxf(fmaxf(sm[4], sm[5]), fmaxf(sm[6], sm[7]));
    // sin(pi*u) = hw_sin(u/2)   [v_sin_f32 takes revolutions]
    const float sscale = 0.5f / (pmax - pmin + EPS_F);

    // wave-uniform constants
    const float inv2pi = 0.15915494309189535f;
    float c0[2][4], s1[2][4], b2[2][4];
    #pragma unroll
    for (int l = 0; l < 2; ++l)
        #pragma unroll
        for (int q = 0; q < 4; ++q) {
            c0[l][q] = __builtin_amdgcn_cosf(wts[(l * 4 + q) * 3 + 0] * inv2pi);
            s1[l][q] = __builtin_amdgcn_sinf(wts[(l * 4 + q) * 3 + 1] * inv2pi);
            b2[l][q] = wts[(l * 4 + q) * 3 + 2];
        }
    float pwr[4][4], pbr[4];
    #pragma unroll
    for (int o = 0; o < 4; ++o) {
        pbr[o] = pb[o];
        #pragma unroll
        for (int q = 0; q < 4; ++q) pwr[o][q] = pw[o * 4 + q];
    }

    #pragma unroll
    for (int it = 0; it < FITERS; ++it) {
        const int grp = it * FTHR + tid;
        const int b   = grp >> 14;
        const int rem = grp & 16383;
        const int ho  = rem >> 6;
        const int wp  = rem & 63;

        float e[4][4];
        #pragma unroll
        for (int p = 0; p < 4; ++p) {
            e[p][0] = __low2float(g[it][2 * p]);     e[p][1] = __high2float(g[it][2 * p]);
            e[p][2] = __low2float(g[it][2 * p + 1]); e[p][3] = __high2float(g[it][2 * p + 1]);
        }
        #pragma unroll
        for (int p = 0; p < 4; ++p)
            #pragma unroll
            for (int q = 0; q < 4; ++q)
                e[p][q] = __builtin_amdgcn_sinf((e[p][q] - pmin) * sscale);
        #pragma unroll
        for (int l = 0; l < 2; ++l)
            #pragma unroll
            for (int p = 0; p < 4; ++p) {
                float mq[4];
                #pragma unroll
                for (int q = 0; q < 4; ++q)
                    mq[q] = e[p][q] * c0[l][q] + e[p][(q + 1) & 3] * s1[l][q] + b2[l][q];
                #pragma unroll
                for (int q = 0; q < 4; ++q) e[p][q] = fast_tanh(mq[q]);
            }

        float* ob = out + b * (4 * HOWO) + ho * WO + 4 * wp;
        #pragma unroll
        for (int o = 0; o < 4; ++o) {
            float4 v;
            float* vp = &v.x;
            #pragma unroll
            for (int p = 0; p < 4; ++p) {
                float acc = pbr[o];
                #pragma unroll
                for (int q = 0; q < 4; ++q) acc += e[p][q] * pwr[o][q];
                vp[p] = acc;
            }
            *(float4*)(ob + o * HOWO) = v;
        }
    }
}

// ============================ FALLBACK PATH (verified 3-kernel) ============================
__global__ __launch_bounds__(TPB) void k_pass1(const float* __restrict__ x,
                                               float4* __restrict__ gray4,
                                               float* __restrict__ part) {
    const int tid = blockIdx.x * TPB + threadIdx.x;
    const float c13 = 1.0f / 3.0f;
    float vmin = __int_as_float(0x7F800000);
    float vmax = __int_as_float(0xFF800000);

    #pragma unroll
    for (int it = 0; it < AITERS; ++it) {
        int grp = it * AT + tid;
        int b   = grp >> 14;
        int rem = grp & 16383;
        int ho  = rem >> 6;
        int wp  = rem & 63;
        const float* base = x + b * (CH * HW) + (2 * ho) * WW + 8 * wp;

        float row0[8], row1[8];
        #pragma unroll
        for (int c = 0; c < CH; ++c) {
            const float* pc = base + c * HW;
            float4 u0 = *(const float4*)(pc);
            float4 u1 = *(const float4*)(pc + 4);
            float4 v0 = *(const float4*)(pc + WW);
            float4 v1 = *(const float4*)(pc + WW + 4);
            float uu[8] = {u0.x, u0.y, u0.z, u0.w, u1.x, u1.y, u1.z, u1.w};
            float vv[8] = {v0.x, v0.y, v0.z, v0.w, v1.x, v1.y, v1.z, v1.w};
            if (c == 0) {
                #pragma unroll
                for (int k = 0; k < 8; ++k) { row0[k] = uu[k]; row1[k] = vv[k]; }
            } else {
                #pragma unroll
                for (int k = 0; k < 8; ++k) { row0[k] += uu[k]; row1[k] += vv[k]; }
            }
        }
        #pragma unroll
        for (int k = 0; k < 8; ++k) {
            row0[k] *= c13; row1[k] *= c13;
            vmin = fminf(vmin, fminf(row0[k], row1[k]));
            vmax = fmaxf(vmax, fmaxf(row0[k], row1[k]));
        }
        alignas(16) __half2 h2[8];
        #pragma unroll
        for (int p = 0; p < 4; ++p) {
            h2[2 * p]     = __floats2half2_rn(row0[2 * p], row0[2 * p + 1]);
            h2[2 * p + 1] = __floats2half2_rn(row1[2 * p], row1[2 * p + 1]);
        }
        gray4[(size_t)grp * 2]     = *(const float4*)&h2[0];
        gray4[(size_t)grp * 2 + 1] = *(const float4*)&h2[4];
    }

    #pragma unroll
    for (int off = 32; off > 0; off >>= 1) {
        vmin = fminf(vmin, __shfl_down(vmin, off, 64));
        vmax = fmaxf(vmax, __shfl_down(vmax, off, 64));
    }
    __shared__ float sm[8];
    int lane = threadIdx.x & 63, wid = threadIdx.x >> 6;
    if (lane == 0) { sm[wid] = vmin; sm[4 + wid] = vmax; }
    __syncthreads();
    if (threadIdx.x == 0) {
        part[2 * blockIdx.x]     = fminf(fminf(sm[0], sm[1]), fminf(sm[2], sm[3]));
        part[2 * blockIdx.x + 1] = fmaxf(fmaxf(sm[4], sm[5]), fmaxf(sm[6], sm[7]));
    }
}

__global__ __launch_bounds__(TPB) void k_reduce(const float* __restrict__ part,
                                                float* __restrict__ mm) {
    float m = __int_as_float(0x7F800000);
    float M = __int_as_float(0xFF800000);
    #pragma unroll
    for (int i = 0; i < ABLOCKS / TPB; ++i) {
        int j = i * TPB + threadIdx.x;
        m = fminf(m, part[2 * j]);
        M = fmaxf(M, part[2 * j + 1]);
    }
    #pragma unroll
    for (int off = 32; off > 0; off >>= 1) {
        m = fminf(m, __shfl_down(m, off, 64));
        M = fmaxf(M, __shfl_down(M, off, 64));
    }
    __shared__ float sm[8];
    int lane = threadIdx.x & 63, wid = threadIdx.x >> 6;
    if (lane == 0) { sm[wid] = m; sm[4 + wid] = M; }
    __syncthreads();
    if (threadIdx.x == 0) {
        mm[0] = fminf(fminf(sm[0], sm[1]), fminf(sm[2], sm[3]));
        mm[1] = fmaxf(fmaxf(sm[4], sm[5]), fmaxf(sm[6], sm[7]));
    }
}

__global__ __launch_bounds__(TPB) void k_main(const float4* __restrict__ gray4,
                                              const float* __restrict__ wts,
                                              const float* __restrict__ pw,
                                              const float* __restrict__ pb,
                                              const float* __restrict__ mm,
                                              float* __restrict__ out) {
    int grp = blockIdx.x * TPB + threadIdx.x;
    int b   = grp >> 14;
    int rem = grp & 16383;
    int ho  = rem >> 6;
    int wp  = rem & 63;

    float pmin   = mm[0];
    float sscale = 0.5f / (mm[1] - pmin + EPS_F);

    const float inv2pi = 0.15915494309189535f;
    float c0[2][4], s1[2][4], b2[2][4];
    #pragma unroll
    for (int l = 0; l < 2; ++l)
        #pragma unroll
        for (int q = 0; q < 4; ++q) {
            c0[l][q] = __builtin_amdgcn_cosf(wts[(l * 4 + q) * 3 + 0] * inv2pi);
            s1[l][q] = __builtin_amdgcn_sinf(wts[(l * 4 + q) * 3 + 1] * inv2pi);
            b2[l][q] = wts[(l * 4 + q) * 3 + 2];
        }
    float pwr[4][4], pbr[4];
    #pragma unroll
    for (int o = 0; o < 4; ++o) {
        pbr[o] = pb[o];
        #pragma unroll
        for (int q = 0; q < 4; ++q) pwr[o][q] = pw[o * 4 + q];
    }

    alignas(16) __half2 h2[8];
    *(float4*)&h2[0] = gray4[(size_t)grp * 2];
    *(float4*)&h2[4] = gray4[(size_t)grp * 2 + 1];

    float e[4][4];
    #pragma unroll
    for (int p = 0; p < 4; ++p) {
        e[p][0] = __low2float(h2[2 * p]);     e[p][1] = __high2float(h2[2 * p]);
        e[p][2] = __low2float(h2[2 * p + 1]); e[p][3] = __high2float(h2[2 * p + 1]);
    }
    #pragma unroll
    for (int p = 0; p < 4; ++p)
        #pragma unroll
        for (int q = 0; q < 4; ++q)
            e[p][q] = __builtin_amdgcn_sinf((e[p][q] - pmin) * sscale);
    #pragma unroll
    for (int l = 0; l < 2; ++l)
        #pragma unroll
        for (int p = 0; p < 4; ++p) {
            float mq[4];
            #pragma unroll
            for (int q = 0; q < 4; ++q)
                mq[q] = e[p][q] * c0[l][q] + e[p][(q + 1) & 3] * s1[l][q] + b2[l][q];
            #pragma unroll
            for (int q = 0; q < 4; ++q) e[p][q] = fast_tanh(mq[q]);
        }

    float* ob = out + b * (4 * HOWO) + ho * WO + 4 * wp;
    #pragma unroll
    for (int o = 0; o < 4; ++o) {
        float4 v;
        float* vp = &v.x;
        #pragma unroll
        for (int p = 0; p < 4; ++p) {
            float acc = pbr[o];
            #pragma unroll
            for (int q = 0; q < 4; ++q) acc += e[p][q] * pwr[o][q];
            vp[p] = acc;
        }
        *(float4*)(ob + o * HOWO) = v;
    }
}

extern "C" void kernel_launch(void* const* d_in, const int* in_sizes, int n_in,
                              void* d_out, int out_size, void* d_ws, size_t ws_size,
                              hipStream_t stream) {
    const float* x   = (const float*)d_in[0];
    const float* wts = (const float*)d_in[1];
    const float* pw  = (const float*)d_in[2];
    const float* pb  = (const float*)d_in[3];
    float* out  = (float*)d_out;
    float* part = (float*)d_ws;   // 8 KB of per-block min/max partials

    void* args[] = {(void*)&x, (void*)&wts, (void*)&pw, (void*)&pb,
                    (void*)&part, (void*)&out};
    hipError_t err = hipLaunchCooperativeKernel((const void*)k_fused, dim3(FBLK),
                                                dim3(TPB), args, 0, stream);
    if (err != hipSuccess) {
        // fallback: previous verified 3-kernel path (distinct ws layout; only one path runs)
        float4* gray4 = (float4*)d_ws;
        float*  fpart = (float*)((char*)d_ws + GRAY_HALFS * sizeof(__half));
        float*  mm    = fpart + 2 * ABLOCKS;
        k_pass1 <<<ABLOCKS, TPB, 0, stream>>>(x, gray4, fpart);
        k_reduce<<<1,       TPB, 0, stream>>>(fpart, mm);
        k_main  <<<CBLOCKS, TPB, 0, stream>>>(gray4, wts, pw, pb, mm, out);
    }
}

// Round 3
// 309.890 us; speedup vs baseline: 1.4200x; 1.4200x over previous
//
#include <hip/hip_runtime.h>
#include <hip/hip_fp16.h>

// Problem constants
constexpr int BN = 64, CH = 3, HH = 512, WW = 512;
constexpr int HO = 256, WO = 256;
constexpr int HW = HH * WW;              // 262144
constexpr int HOWO = HO * WO;            // 65536
constexpr float EPS_F = 1e-8f;

constexpr int TPB = 256;
constexpr int GROUPS = BN * HO * (WO / 4);   // 1,048,576 groups of 4 patches
constexpr int ABLOCKS = 2048;
constexpr int AT = ABLOCKS * TPB;            // 524,288 threads
constexpr int AITERS = GROUPS / AT;          // 2
constexpr int CBLOCKS = GROUPS / TPB;        // 4096

// native vector type for nontemporal builtin (HIP float4 is a class, rejected)
typedef float floatx4 __attribute__((ext_vector_type(4)));

// ws layout: [gray fp16: GROUPS*16 halfs = 32 MiB][part_min: 2048 f][part_max: 2048 f]
constexpr size_t GRAY_HALFS = (size_t)GROUPS * 16;

// tanh(x) = 1 - 2/(e^{2x}+1) via hw exp2 + rcp (abs err ~1e-6, saturates correctly)
__device__ __forceinline__ float fast_tanh(float x) {
    float t = __builtin_amdgcn_exp2f(x * 2.8853900817779268f);  // e^{2x}
    return 1.0f - 2.0f * __builtin_amdgcn_rcpf(t + 1.0f);
}

// Pass 1: gray = mean(x, C); write fp16 gray to ws; per-block min/max partials
// (split arrays so pass 2 can reduce them with vectorized float4 loads).
__global__ __launch_bounds__(TPB) void k_pass1(const float* __restrict__ x,
                                               float4* __restrict__ gray4,
                                               float* __restrict__ part_min,
                                               float* __restrict__ part_max) {
    const int tid = blockIdx.x * TPB + threadIdx.x;
    const float c13 = 1.0f / 3.0f;
    float vmin = __int_as_float(0x7F800000);
    float vmax = __int_as_float(0xFF800000);

    #pragma unroll
    for (int it = 0; it < AITERS; ++it) {
        int grp = it * AT + tid;         // group of 4 consecutive patches
        int b   = grp >> 14;             // 16384 groups per image
        int rem = grp & 16383;
        int ho  = rem >> 6;              // 64 groups per patch-row
        int wp  = rem & 63;
        const float* base = x + b * (CH * HW) + (2 * ho) * WW + 8 * wp;

        float row0[8], row1[8];
        #pragma unroll
        for (int c = 0; c < CH; ++c) {
            const float* pc = base + c * HW;
            float4 u0 = *(const float4*)(pc);
            float4 u1 = *(const float4*)(pc + 4);
            float4 v0 = *(const float4*)(pc + WW);
            float4 v1 = *(const float4*)(pc + WW + 4);
            float uu[8] = {u0.x, u0.y, u0.z, u0.w, u1.x, u1.y, u1.z, u1.w};
            float vv[8] = {v0.x, v0.y, v0.z, v0.w, v1.x, v1.y, v1.z, v1.w};
            if (c == 0) {
                #pragma unroll
                for (int k = 0; k < 8; ++k) { row0[k] = uu[k]; row1[k] = vv[k]; }
            } else {
                #pragma unroll
                for (int k = 0; k < 8; ++k) { row0[k] += uu[k]; row1[k] += vv[k]; }
            }
        }
        #pragma unroll
        for (int k = 0; k < 8; ++k) {
            row0[k] *= c13; row1[k] *= c13;
            vmin = fminf(vmin, fminf(row0[k], row1[k]));
            vmax = fmaxf(vmax, fmaxf(row0[k], row1[k]));
        }
        // pack 16 grays: per patch p: h2[2p]=(r0c0,r0c1), h2[2p+1]=(r1c0,r1c1)
        alignas(16) __half2 h2[8];
        #pragma unroll
        for (int p = 0; p < 4; ++p) {
            h2[2 * p]     = __floats2half2_rn(row0[2 * p], row0[2 * p + 1]);
            h2[2 * p + 1] = __floats2half2_rn(row1[2 * p], row1[2 * p + 1]);
        }
        gray4[(size_t)grp * 2]     = *(const float4*)&h2[0];
        gray4[(size_t)grp * 2 + 1] = *(const float4*)&h2[4];
    }

    // wave + block min/max reduce (deterministic)
    #pragma unroll
    for (int off = 32; off > 0; off >>= 1) {
        vmin = fminf(vmin, __shfl_down(vmin, off, 64));
        vmax = fmaxf(vmax, __shfl_down(vmax, off, 64));
    }
    __shared__ float sm[8];
    int lane = threadIdx.x & 63, wid = threadIdx.x >> 6;
    if (lane == 0) { sm[wid] = vmin; sm[4 + wid] = vmax; }
    __syncthreads();
    if (threadIdx.x == 0) {
        part_min[blockIdx.x] = fminf(fminf(sm[0], sm[1]), fminf(sm[2], sm[3]));
        part_max[blockIdx.x] = fmaxf(fmaxf(sm[4], sm[5]), fmaxf(sm[6], sm[7]));
    }
}

// Pass 2: redundant per-block reduce of the 2048 partial pairs (16 KB, L3-hot,
// deterministic — no k_reduce launch/bubble), then quantum chain + projection.
// Gray loads are issued BEFORE the reduce so HBM/L3 latency hides under it.
__global__ __launch_bounds__(TPB) void k_main(const float4* __restrict__ gray4,
                                              const float* __restrict__ wts,
                                              const float* __restrict__ pw,
                                              const float* __restrict__ pb,
                                              const float4* __restrict__ pmin4,
                                              const float4* __restrict__ pmax4,
                                              float* __restrict__ out) {
    const int grp = blockIdx.x * TPB + threadIdx.x;    // exact grid: GROUPS
    const int b   = grp >> 14;
    const int rem = grp & 16383;
    const int ho  = rem >> 6;
    const int wp  = rem & 63;

    // issue payload loads first (latency hidden under the reduce below)
    alignas(16) __half2 h2[8];
    *(float4*)&h2[0] = gray4[(size_t)grp * 2];
    *(float4*)&h2[4] = gray4[(size_t)grp * 2 + 1];

    // redundant block-level min/max reduce: 2048 floats per array = 512 float4
    float4 a0 = pmin4[threadIdx.x], a1 = pmin4[threadIdx.x + 256];
    float4 b0 = pmax4[threadIdx.x], b1 = pmax4[threadIdx.x + 256];
    float m = fminf(fminf(fminf(a0.x, a0.y), fminf(a0.z, a0.w)),
                    fminf(fminf(a1.x, a1.y), fminf(a1.z, a1.w)));
    float M = fmaxf(fmaxf(fmaxf(b0.x, b0.y), fmaxf(b0.z, b0.w)),
                    fmaxf(fmaxf(b1.x, b1.y), fmaxf(b1.z, b1.w)));
    #pragma unroll
    for (int off = 32; off > 0; off >>= 1) {
        m = fminf(m, __shfl_down(m, off, 64));
        M = fmaxf(M, __shfl_down(M, off, 64));
    }
    __shared__ float sm[8];
    const int lane = threadIdx.x & 63, wid = threadIdx.x >> 6;
    if (lane == 0) { sm[wid] = m; sm[4 + wid] = M; }
    __syncthreads();
    const float pmin = fminf(fminf(sm[0], sm[1]), fminf(sm[2], sm[3]));
    const float pmax = fmaxf(fmaxf(sm[4], sm[5]), fmaxf(sm[6], sm[7]));
    // sin(pi*u) = hw_sin(u/2)   [v_sin_f32 takes revolutions]
    const float sscale = 0.5f / (pmax - pmin + EPS_F);

    // wave-uniform constants
    const float inv2pi = 0.15915494309189535f;
    float c0[2][4], s1[2][4], b2[2][4];
    #pragma unroll
    for (int l = 0; l < 2; ++l)
        #pragma unroll
        for (int q = 0; q < 4; ++q) {
            c0[l][q] = __builtin_amdgcn_cosf(wts[(l * 4 + q) * 3 + 0] * inv2pi);
            s1[l][q] = __builtin_amdgcn_sinf(wts[(l * 4 + q) * 3 + 1] * inv2pi);
            b2[l][q] = wts[(l * 4 + q) * 3 + 2];
        }
    float pwr[4][4], pbr[4];
    #pragma unroll
    for (int o = 0; o < 4; ++o) {
        pbr[o] = pb[o];
        #pragma unroll
        for (int q = 0; q < 4; ++q) pwr[o][q] = pw[o * 4 + q];
    }

    float e[4][4];
    #pragma unroll
    for (int p = 0; p < 4; ++p) {
        e[p][0] = __low2float(h2[2 * p]);     e[p][1] = __high2float(h2[2 * p]);
        e[p][2] = __low2float(h2[2 * p + 1]); e[p][3] = __high2float(h2[2 * p + 1]);
    }
    #pragma unroll
    for (int p = 0; p < 4; ++p)
        #pragma unroll
        for (int q = 0; q < 4; ++q)
            e[p][q] = __builtin_amdgcn_sinf((e[p][q] - pmin) * sscale);
    #pragma unroll
    for (int l = 0; l < 2; ++l)
        #pragma unroll
        for (int p = 0; p < 4; ++p) {
            float mq[4];
            #pragma unroll
            for (int q = 0; q < 4; ++q)
                mq[q] = e[p][q] * c0[l][q] + e[p][(q + 1) & 3] * s1[l][q] + b2[l][q];
            #pragma unroll
            for (int q = 0; q < 4; ++q) e[p][q] = fast_tanh(mq[q]);
        }

    // non-temporal stores: out is never re-read; keep x/gray resident in L3
    float* ob = out + b * (4 * HOWO) + ho * WO + 4 * wp;
    #pragma unroll
    for (int o = 0; o < 4; ++o) {
        floatx4 v;
        #pragma unroll
        for (int p = 0; p < 4; ++p) {
            float acc = pbr[o];
            #pragma unroll
            for (int q = 0; q < 4; ++q) acc += e[p][q] * pwr[o][q];
            v[p] = acc;
        }
        __builtin_nontemporal_store(v, (floatx4*)(ob + o * HOWO));
    }
}

extern "C" void kernel_launch(void* const* d_in, const int* in_sizes, int n_in,
                              void* d_out, int out_size, void* d_ws, size_t ws_size,
                              hipStream_t stream) {
    const float* x   = (const float*)d_in[0];
    const float* wts = (const float*)d_in[1];
    const float* pw  = (const float*)d_in[2];
    const float* pb  = (const float*)d_in[3];
    float* out = (float*)d_out;

    float4* gray4    = (float4*)d_ws;
    float*  part_min = (float*)((char*)d_ws + GRAY_HALFS * sizeof(__half));
    float*  part_max = part_min + ABLOCKS;

    k_pass1<<<ABLOCKS, TPB, 0, stream>>>(x, gray4, part_min, part_max);
    k_main <<<CBLOCKS, TPB, 0, stream>>>(gray4, wts, pw, pb,
                                         (const float4*)part_min,
                                         (const float4*)part_max, out);
}

// Round 4
// 306.391 us; speedup vs baseline: 1.4363x; 1.0114x over previous
//
#include <hip/hip_runtime.h>
#include <hip/hip_fp16.h>

// Problem constants
constexpr int BN = 64, CH = 3, HH = 512, WW = 512;
constexpr int HO = 256, WO = 256;
constexpr int HW = HH * WW;              // 262144
constexpr int HOWO = HO * WO;            // 65536
constexpr float EPS_F = 1e-8f;

constexpr int TPB = 256;
constexpr int GROUPS = BN * HO * (WO / 4);   // 1,048,576 groups of 4 patches
constexpr int ABLOCKS = 2048;
constexpr int AT = ABLOCKS * TPB;            // 524,288 threads
constexpr int AITERS = GROUPS / AT;          // 2
constexpr int CBLOCKS = GROUPS / TPB;        // 4096

// native vector type for nontemporal builtins (HIP float4 is a class, rejected)
typedef float floatx4 __attribute__((ext_vector_type(4)));

// ws layout: [gray fp16: GROUPS*16 halfs = 32 MiB][part_min: 2048 f][part_max: 2048 f]
constexpr size_t GRAY_HALFS = (size_t)GROUPS * 16;

// tanh(x) = 1 - 2/(e^{2x}+1) via hw exp2 + rcp (abs err ~1e-6, saturates correctly)
__device__ __forceinline__ float fast_tanh(float x) {
    float t = __builtin_amdgcn_exp2f(x * 2.8853900817779268f);  // e^{2x}
    return 1.0f - 2.0f * __builtin_amdgcn_rcpf(t + 1.0f);
}

// Pass 1: gray = mean(x, C); write fp16 gray to ws; per-block min/max partials.
// x is streamed with NON-TEMPORAL loads (touched exactly once) so the freshly
// written gray lines stay resident in L2/L3 for k_main instead of being
// evicted + written back to HBM by the 201 MB x sweep.
__global__ __launch_bounds__(TPB) void k_pass1(const float* __restrict__ x,
                                               float4* __restrict__ gray4,
                                               float* __restrict__ part_min,
                                               float* __restrict__ part_max) {
    const int tid = blockIdx.x * TPB + threadIdx.x;
    const float c13 = 1.0f / 3.0f;
    float vmin = __int_as_float(0x7F800000);
    float vmax = __int_as_float(0xFF800000);

    #pragma unroll
    for (int it = 0; it < AITERS; ++it) {
        int grp = it * AT + tid;         // group of 4 consecutive patches
        int b   = grp >> 14;             // 16384 groups per image
        int rem = grp & 16383;
        int ho  = rem >> 6;              // 64 groups per patch-row
        int wp  = rem & 63;
        const float* base = x + b * (CH * HW) + (2 * ho) * WW + 8 * wp;

        float row0[8], row1[8];
        #pragma unroll
        for (int c = 0; c < CH; ++c) {
            const float* pc = base + c * HW;
            floatx4 u0 = __builtin_nontemporal_load((const floatx4*)(pc));
            floatx4 u1 = __builtin_nontemporal_load((const floatx4*)(pc + 4));
            floatx4 v0 = __builtin_nontemporal_load((const floatx4*)(pc + WW));
            floatx4 v1 = __builtin_nontemporal_load((const floatx4*)(pc + WW + 4));
            float uu[8] = {u0[0], u0[1], u0[2], u0[3], u1[0], u1[1], u1[2], u1[3]};
            float vv[8] = {v0[0], v0[1], v0[2], v0[3], v1[0], v1[1], v1[2], v1[3]};
            if (c == 0) {
                #pragma unroll
                for (int k = 0; k < 8; ++k) { row0[k] = uu[k]; row1[k] = vv[k]; }
            } else {
                #pragma unroll
                for (int k = 0; k < 8; ++k) { row0[k] += uu[k]; row1[k] += vv[k]; }
            }
        }
        #pragma unroll
        for (int k = 0; k < 8; ++k) {
            row0[k] *= c13; row1[k] *= c13;
            vmin = fminf(vmin, fminf(row0[k], row1[k]));
            vmax = fmaxf(vmax, fmaxf(row0[k], row1[k]));
        }
        // pack 16 grays: per patch p: h2[2p]=(r0c0,r0c1), h2[2p+1]=(r1c0,r1c1)
        alignas(16) __half2 h2[8];
        #pragma unroll
        for (int p = 0; p < 4; ++p) {
            h2[2 * p]     = __floats2half2_rn(row0[2 * p], row0[2 * p + 1]);
            h2[2 * p + 1] = __floats2half2_rn(row1[2 * p], row1[2 * p + 1]);
        }
        gray4[(size_t)grp * 2]     = *(const float4*)&h2[0];
        gray4[(size_t)grp * 2 + 1] = *(const float4*)&h2[4];
    }

    // wave + block min/max reduce (deterministic)
    #pragma unroll
    for (int off = 32; off > 0; off >>= 1) {
        vmin = fminf(vmin, __shfl_down(vmin, off, 64));
        vmax = fmaxf(vmax, __shfl_down(vmax, off, 64));
    }
    __shared__ float sm[8];
    int lane = threadIdx.x & 63, wid = threadIdx.x >> 6;
    if (lane == 0) { sm[wid] = vmin; sm[4 + wid] = vmax; }
    __syncthreads();
    if (threadIdx.x == 0) {
        part_min[blockIdx.x] = fminf(fminf(sm[0], sm[1]), fminf(sm[2], sm[3]));
        part_max[blockIdx.x] = fmaxf(fmaxf(sm[4], sm[5]), fmaxf(sm[6], sm[7]));
    }
}

// Pass 2: redundant per-block reduce of the 2048 partial pairs (16 KB, L2-hot,
// deterministic — no k_reduce launch/bubble), then quantum chain + projection.
// Gray loads are issued BEFORE the reduce so their latency hides under it.
__global__ __launch_bounds__(TPB) void k_main(const float4* __restrict__ gray4,
                                              const float* __restrict__ wts,
                                              const float* __restrict__ pw,
                                              const float* __restrict__ pb,
                                              const float4* __restrict__ pmin4,
                                              const float4* __restrict__ pmax4,
                                              float* __restrict__ out) {
    const int grp = blockIdx.x * TPB + threadIdx.x;    // exact grid: GROUPS
    const int b   = grp >> 14;
    const int rem = grp & 16383;
    const int ho  = rem >> 6;
    const int wp  = rem & 63;

    // issue payload loads first (latency hidden under the reduce below)
    alignas(16) __half2 h2[8];
    *(float4*)&h2[0] = gray4[(size_t)grp * 2];
    *(float4*)&h2[4] = gray4[(size_t)grp * 2 + 1];

    // redundant block-level min/max reduce: 2048 floats per array = 512 float4
    float4 a0 = pmin4[threadIdx.x], a1 = pmin4[threadIdx.x + 256];
    float4 b0 = pmax4[threadIdx.x], b1 = pmax4[threadIdx.x + 256];
    float m = fminf(fminf(fminf(a0.x, a0.y), fminf(a0.z, a0.w)),
                    fminf(fminf(a1.x, a1.y), fminf(a1.z, a1.w)));
    float M = fmaxf(fmaxf(fmaxf(b0.x, b0.y), fmaxf(b0.z, b0.w)),
                    fmaxf(fmaxf(b1.x, b1.y), fmaxf(b1.z, b1.w)));
    #pragma unroll
    for (int off = 32; off > 0; off >>= 1) {
        m = fminf(m, __shfl_down(m, off, 64));
        M = fmaxf(M, __shfl_down(M, off, 64));
    }
    __shared__ float sm[8];
    const int lane = threadIdx.x & 63, wid = threadIdx.x >> 6;
    if (lane == 0) { sm[wid] = m; sm[4 + wid] = M; }
    __syncthreads();
    const float pmin = fminf(fminf(sm[0], sm[1]), fminf(sm[2], sm[3]));
    const float pmax = fmaxf(fmaxf(sm[4], sm[5]), fmaxf(sm[6], sm[7]));
    // sin(pi*u) = hw_sin(u/2)   [v_sin_f32 takes revolutions]
    const float sscale = 0.5f / (pmax - pmin + EPS_F);

    // wave-uniform constants
    const float inv2pi = 0.15915494309189535f;
    float c0[2][4], s1[2][4], b2[2][4];
    #pragma unroll
    for (int l = 0; l < 2; ++l)
        #pragma unroll
        for (int q = 0; q < 4; ++q) {
            c0[l][q] = __builtin_amdgcn_cosf(wts[(l * 4 + q) * 3 + 0] * inv2pi);
            s1[l][q] = __builtin_amdgcn_sinf(wts[(l * 4 + q) * 3 + 1] * inv2pi);
            b2[l][q] = wts[(l * 4 + q) * 3 + 2];
        }
    float pwr[4][4], pbr[4];
    #pragma unroll
    for (int o = 0; o < 4; ++o) {
        pbr[o] = pb[o];
        #pragma unroll
        for (int q = 0; q < 4; ++q) pwr[o][q] = pw[o * 4 + q];
    }

    float e[4][4];
    #pragma unroll
    for (int p = 0; p < 4; ++p) {
        e[p][0] = __low2float(h2[2 * p]);     e[p][1] = __high2float(h2[2 * p]);
        e[p][2] = __low2float(h2[2 * p + 1]); e[p][3] = __high2float(h2[2 * p + 1]);
    }
    #pragma unroll
    for (int p = 0; p < 4; ++p)
        #pragma unroll
        for (int q = 0; q < 4; ++q)
            e[p][q] = __builtin_amdgcn_sinf((e[p][q] - pmin) * sscale);
    #pragma unroll
    for (int l = 0; l < 2; ++l)
        #pragma unroll
        for (int p = 0; p < 4; ++p) {
            float mq[4];
            #pragma unroll
            for (int q = 0; q < 4; ++q)
                mq[q] = e[p][q] * c0[l][q] + e[p][(q + 1) & 3] * s1[l][q] + b2[l][q];
            #pragma unroll
            for (int q = 0; q < 4; ++q) e[p][q] = fast_tanh(mq[q]);
        }

    // non-temporal stores: out is never re-read; keep x/gray resident in L3
    float* ob = out + b * (4 * HOWO) + ho * WO + 4 * wp;
    #pragma unroll
    for (int o = 0; o < 4; ++o) {
        floatx4 v;
        #pragma unroll
        for (int p = 0; p < 4; ++p) {
            float acc = pbr[o];
            #pragma unroll
            for (int q = 0; q < 4; ++q) acc += e[p][q] * pwr[o][q];
            v[p] = acc;
        }
        __builtin_nontemporal_store(v, (floatx4*)(ob + o * HOWO));
    }
}

extern "C" void kernel_launch(void* const* d_in, const int* in_sizes, int n_in,
                              void* d_out, int out_size, void* d_ws, size_t ws_size,
                              hipStream_t stream) {
    const float* x   = (const float*)d_in[0];
    const float* wts = (const float*)d_in[1];
    const float* pw  = (const float*)d_in[2];
    const float* pb  = (const float*)d_in[3];
    float* out = (float*)d_out;

    float4* gray4    = (float4*)d_ws;
    float*  part_min = (float*)((char*)d_ws + GRAY_HALFS * sizeof(__half));
    float*  part_max = part_min + ABLOCKS;

    k_pass1<<<ABLOCKS, TPB, 0, stream>>>(x, gray4, part_min, part_max);
    k_main <<<CBLOCKS, TPB, 0, stream>>>(gray4, wts, pw, pb,
                                         (const float4*)part_min,
                                         (const float4*)part_max, out);
}